// Round 2
// baseline (321.880 us; speedup 1.0000x reference)
//
#include <hip/hip_runtime.h>
#include <stdint.h>

// x: (32, 256, 58, 58) f32 binary {0,1};  w: (256, 256, 3, 3) f32
// out: (32, 256, 56, 56) f32 = alpha[o]*(2S - 2304), S = XNOR matches
// out = fma(-2*alpha[o], P, 2304*alpha[o]),  P = popcount(xbits ^ wbits)

#define BATCH 32
#define C_IN 256
#define OCH 256
#define HIN 58
#define WIN2 58
#define HOUT 56
#define WOUT 56
#define TAPS 9
#define WWORDS 8            // 256 channels / 32 bits
#define HWIN (HIN * WIN2)   // 3364
#define HWOUT (HOUT * WOUT) // 3136
#define NPOS (BATCH * HWIN) // 107648
#define OGRP 32             // o-channels per block (8 groups)

// ---------------------------------------------------------------------------
// Kernel 1: bit-pack x along channels. Thread ↔ (position p, word-pair wp).
// Reads 64B-coalesced per (wp,j) group; writes fully contiguous uint2/wave.
// ---------------------------------------------------------------------------
__global__ __launch_bounds__(256) void pack_x_kernel(
    const float* __restrict__ x, uint32_t* __restrict__ xp)
{
    int t = blockIdx.x * 256 + threadIdx.x;      // 1682 blocks exactly
    int p  = t >> 2;                             // position in [0, NPOS)
    int wp = t & 3;                              // word pair
    int b = p / HWIN;
    int r = p - b * HWIN;
    const float* xb = x + ((size_t)(b * C_IN + wp * 64)) * HWIN + r;
    uint32_t m0 = 0u, m1 = 0u;
    #pragma unroll
    for (int j = 0; j < 32; ++j) {
        float v0 = xb[(size_t)j * HWIN];
        float v1 = xb[(size_t)(j + 32) * HWIN];
        m0 |= (v0 > 0.5f ? 1u : 0u) << j;        // word 2wp,   bit j = ch 64wp+j
        m1 |= (v1 > 0.5f ? 1u : 0u) << j;        // word 2wp+1, bit j = ch 64wp+32+j
    }
    *(uint2*)(xp + (size_t)p * WWORDS + wp * 2) = make_uint2(m0, m1);
}

// ---------------------------------------------------------------------------
// Kernel 2: pack weights TAP-MAJOR (wq[tap][o][8]) + per-o scale/bias.
// ---------------------------------------------------------------------------
__global__ __launch_bounds__(256) void pack_w_kernel(
    const float* __restrict__ wt, uint32_t* __restrict__ wq,
    float* __restrict__ sA, float* __restrict__ sB)
{
    int o = blockIdx.x;
    int c = threadIdx.x;
    const float* wb = wt + ((size_t)o * C_IN + c) * TAPS;
    float wv[TAPS];
    float s = 0.f;
    #pragma unroll
    for (int t = 0; t < TAPS; ++t) {
        wv[t] = wb[t];
        s += fabsf(wv[t]);
    }
    int wave = c >> 6, lane = c & 63;
    #pragma unroll
    for (int t = 0; t < TAPS; ++t) {
        unsigned long long m = __ballot(wv[t] >= 0.0f);
        if (lane == 0) {
            wq[((size_t)t * OCH + o) * WWORDS + wave * 2]     = (uint32_t)m;
            wq[((size_t)t * OCH + o) * WWORDS + wave * 2 + 1] = (uint32_t)(m >> 32);
        }
    }
    __shared__ float red[256];
    red[c] = s;
    __syncthreads();
    for (int off = 128; off > 0; off >>= 1) {
        if (c < off) red[c] += red[c + off];
        __syncthreads();
    }
    if (c == 0) {
        float alpha = red[0] / (float)(C_IN * HWIN);   // n = C*H*W per reference
        sA[o] = -2.0f * alpha;
        sB[o] = (float)(C_IN * TAPS) * alpha;          // 2304 * alpha
    }
}

// ---------------------------------------------------------------------------
// Kernel 3: main. Thread ↔ output position; 32 o-channels per block.
// R5: weights moved LDS -> SGPRs. R4 analysis: 576 broadcast ds_read_b128
// per wave each cost a full 1KiB LDS-return (8-12cyc/CU) -> LDS pipe was
// 63-94% occupied, the true limiter (VALUBusy=85 is the gfx94x-formula 2x
// overstatement; real VALU demand is only ~50us). Weight addresses depend
// only on blockIdx.y/tap/oo (wave-uniform) and all pointers are const
// __restrict__, so these uint4 loads select to s_load_dwordx4 through the
// scalar cache: ZERO LDS traffic, no staging, no __syncthreads, and
// v_xor_b32 takes the weight straight from the SGPR operand slot.
// Inner loop/pair: 16 v_xor + 16 v_bcnt(accumulate) + 1 v_lshl_add = 33.
// ---------------------------------------------------------------------------
__global__ __launch_bounds__(256, 8) void xnor_main_kernel(
    const uint32_t* __restrict__ xp, const uint32_t* __restrict__ wq,
    const float* __restrict__ sA, const float* __restrict__ sB,
    float* __restrict__ out)
{
    int obase = blockIdx.y * OGRP;

    int m = blockIdx.x * 256 + threadIdx.x;      // 392 blocks exactly
    int b = m / HWOUT;
    int r = m - b * HWOUT;
    int oy = r / WOUT;
    int ox = r - oy * WOUT;

    const uint32_t* xrow = xp + (((size_t)b * HIN + oy) * WIN2 + ox) * WWORDS;

    uint32_t acc[OGRP / 2];
    #pragma unroll
    for (int i = 0; i < OGRP / 2; ++i) acc[i] = 0u;

    // tap 0 x-words
    uint4 x0 = *(const uint4*)(xrow);
    uint4 x1 = *(const uint4*)(xrow + 4);

    #pragma unroll 1
    for (int tap = 0; tap < TAPS; ++tap) {
        // Prefetch next tap's x-words (last iter re-reads tap 8: harmless).
        int t2 = (tap < TAPS - 1) ? tap + 1 : TAPS - 1;
        int dy2 = t2 / 3;
        int dx2 = t2 - dy2 * 3;
        const uint32_t* nsrc = xrow + (size_t)(dy2 * WIN2 + dx2) * WWORDS;
        uint4 nx0 = *(const uint4*)(nsrc);
        uint4 nx1 = *(const uint4*)(nsrc + 4);

        // Wave-uniform weight base for this (tap, o-group): -> s_load.
        const uint32_t* wt = wq + ((size_t)tap * OCH + obase) * WWORDS;
        #pragma unroll
        for (int oo = 0; oo < OGRP; oo += 2) {
            uint4 wa  = *(const uint4*)(wt + oo * 8 + 0);   // o-even words 0-3
            uint4 wb2 = *(const uint4*)(wt + oo * 8 + 4);   // o-even words 4-7
            uint4 wc  = *(const uint4*)(wt + oo * 8 + 8);   // o-odd  words 0-3
            uint4 wd  = *(const uint4*)(wt + oo * 8 + 12);  // o-odd  words 4-7
            uint32_t a = acc[oo >> 1];
            // even-o chain, seeded with acc: 8 x (v_xor + v_bcnt(acc))
            a += __popc(wa.x ^ x0.x); a += __popc(wa.y ^ x0.y);
            a += __popc(wa.z ^ x0.z); a += __popc(wa.w ^ x0.w);
            a += __popc(wb2.x ^ x1.x); a += __popc(wb2.y ^ x1.y);
            a += __popc(wb2.z ^ x1.z); a += __popc(wb2.w ^ x1.w);
            // odd-o chain, independent (ILP partner for the seeded chain)
            uint32_t qo = __popc(wc.x ^ x0.x) + __popc(wc.y ^ x0.y)
                        + __popc(wc.z ^ x0.z) + __popc(wc.w ^ x0.w)
                        + __popc(wd.x ^ x1.x) + __popc(wd.y ^ x1.y)
                        + __popc(wd.z ^ x1.z) + __popc(wd.w ^ x1.w);
            acc[oo >> 1] = a + (qo << 16);       // v_lshl_add_u32
        }
        x0 = nx0; x1 = nx1;
    }

    size_t ob = ((size_t)b * OCH + obase) * HWOUT + (size_t)oy * WOUT + ox;
    #pragma unroll
    for (int oo = 0; oo < OGRP; oo += 2) {
        uint32_t a = acc[oo >> 1];
        float P0 = (float)(a & 0xFFFFu);
        float P1 = (float)(a >> 16);
        int o0 = obase + oo;
        out[ob + (size_t)oo * HWOUT]       = fmaf(sA[o0],     P0, sB[o0]);
        out[ob + (size_t)(oo + 1) * HWOUT] = fmaf(sA[o0 + 1], P1, sB[o0 + 1]);
    }
}

// ---------------------------------------------------------------------------
extern "C" void kernel_launch(void* const* d_in, const int* in_sizes, int n_in,
                              void* d_out, int out_size, void* d_ws, size_t ws_size,
                              hipStream_t stream)
{
    const float* x  = (const float*)d_in[0];
    const float* wt = (const float*)d_in[1];
    float* out = (float*)d_out;

    char* ws = (char*)d_ws;
    uint32_t* xp = (uint32_t*)ws;                               // 3,444,736 B
    uint32_t* wq = (uint32_t*)(ws + 3444736);                   //    73,728 B
    float*    sA = (float*)(ws + 3444736 + 73728);              //     1,024 B
    float*    sB = (float*)(ws + 3444736 + 73728 + 1024);       //     1,024 B

    // 1) pack x: 430,592 threads / 256 = 1682 blocks exactly
    pack_x_kernel<<<dim3(1682), dim3(256), 0, stream>>>(x, xp);

    // 2) pack weights (tap-major) + scales
    pack_w_kernel<<<dim3(OCH), dim3(256), 0, stream>>>(wt, wq, sA, sB);

    // 3) main: 392 position-blocks x 8 o-groups of 32
    xnor_main_kernel<<<dim3(392, 8), dim3(256), 0, stream>>>(xp, wq, sA, sB, out);
}

// Round 3
// 296.965 us; speedup vs baseline: 1.0839x; 1.0839x over previous
//
#include <hip/hip_runtime.h>
#include <stdint.h>

// x: (32, 256, 58, 58) f32 binary {0,1};  w: (256, 256, 3, 3) f32
// out: (32, 256, 56, 56) f32 = alpha[o]*(2S - 2304), S = XNOR matches
// out = fma(-2*alpha[o], P, 2304*alpha[o]),  P = popcount(xbits ^ wbits)

#define BATCH 32
#define C_IN 256
#define OCH 256
#define HIN 58
#define WIN2 58
#define HOUT 56
#define WOUT 56
#define TAPS 9
#define WWORDS 8            // 256 channels / 32 bits
#define HWIN (HIN * WIN2)   // 3364
#define HWOUT (HOUT * WOUT) // 3136
#define NPOS (BATCH * HWIN) // 107648
#define OGRP 32             // o-channels per block (8 groups)

// Fused accumulate-popcount: d = popc(s0) + d. The compiler was emitting
// separate v_bcnt + v_add (R2 model: 49 VALU/pair -> 147us predicted = 150us
// measured at the ~1.5GHz sustained-VALU clock). This asm pins 2 VALU/word.
#define BCNT_ACC(a, v) asm("v_bcnt_u32_b32 %0, %1, %0" : "+v"(a) : "v"(v))

// ---------------------------------------------------------------------------
// Kernel 1: bit-pack x along channels. Thread ↔ (position p, word-pair wp).
// Reads 64B-coalesced per (wp,j) group; writes fully contiguous uint2/wave.
// ---------------------------------------------------------------------------
__global__ __launch_bounds__(256) void pack_x_kernel(
    const float* __restrict__ x, uint32_t* __restrict__ xp)
{
    int t = blockIdx.x * 256 + threadIdx.x;      // 1682 blocks exactly
    int p  = t >> 2;                             // position in [0, NPOS)
    int wp = t & 3;                              // word pair
    int b = p / HWIN;
    int r = p - b * HWIN;
    const float* xb = x + ((size_t)(b * C_IN + wp * 64)) * HWIN + r;
    uint32_t m0 = 0u, m1 = 0u;
    #pragma unroll
    for (int j = 0; j < 32; ++j) {
        float v0 = xb[(size_t)j * HWIN];
        float v1 = xb[(size_t)(j + 32) * HWIN];
        m0 |= (v0 > 0.5f ? 1u : 0u) << j;        // word 2wp,   bit j = ch 64wp+j
        m1 |= (v1 > 0.5f ? 1u : 0u) << j;        // word 2wp+1, bit j = ch 64wp+32+j
    }
    *(uint2*)(xp + (size_t)p * WWORDS + wp * 2) = make_uint2(m0, m1);
}

// ---------------------------------------------------------------------------
// Kernel 2: pack weights TAP-MAJOR (wq[tap][o][8]) + per-o scale/bias.
// ---------------------------------------------------------------------------
__global__ __launch_bounds__(256) void pack_w_kernel(
    const float* __restrict__ wt, uint32_t* __restrict__ wq,
    float* __restrict__ sA, float* __restrict__ sB)
{
    int o = blockIdx.x;
    int c = threadIdx.x;
    const float* wb = wt + ((size_t)o * C_IN + c) * TAPS;
    float wv[TAPS];
    float s = 0.f;
    #pragma unroll
    for (int t = 0; t < TAPS; ++t) {
        wv[t] = wb[t];
        s += fabsf(wv[t]);
    }
    int wave = c >> 6, lane = c & 63;
    #pragma unroll
    for (int t = 0; t < TAPS; ++t) {
        unsigned long long m = __ballot(wv[t] >= 0.0f);
        if (lane == 0) {
            wq[((size_t)t * OCH + o) * WWORDS + wave * 2]     = (uint32_t)m;
            wq[((size_t)t * OCH + o) * WWORDS + wave * 2 + 1] = (uint32_t)(m >> 32);
        }
    }
    __shared__ float red[256];
    red[c] = s;
    __syncthreads();
    for (int off = 128; off > 0; off >>= 1) {
        if (c < off) red[c] += red[c + off];
        __syncthreads();
    }
    if (c == 0) {
        float alpha = red[0] / (float)(C_IN * HWIN);   // n = C*H*W per reference
        sA[o] = -2.0f * alpha;
        sB[o] = (float)(C_IN * TAPS) * alpha;          // 2304 * alpha
    }
}

// ---------------------------------------------------------------------------
// Kernel 3: main. Thread ↔ output position; 32 o-channels per block.
// R6: one u32 accumulator PER o-channel (32 total) + inline-asm fused
// v_bcnt_u32_b32 accumulate -> exactly 2 VALU per 32-channel word
// (1 v_xor + 1 fused v_bcnt), the algorithmic VALU floor. No halfword
// packing, no shift-add, no separate adds. Weights stay wave-uniform
// (blockIdx.y/tap/oo only) -> s_load through the scalar cache; v_xor takes
// the SGPR operand directly (1-SGPR-per-VALU rule satisfied).
// VGPR budget: 32 acc + 8 x + 8 prefetch + ~6 addr = ~54 <= 64 -> 8 w/SIMD.
// ---------------------------------------------------------------------------
__global__ __launch_bounds__(256, 8) void xnor_main_kernel(
    const uint32_t* __restrict__ xp, const uint32_t* __restrict__ wq,
    const float* __restrict__ sA, const float* __restrict__ sB,
    float* __restrict__ out)
{
    int obase = blockIdx.y * OGRP;

    int m = blockIdx.x * 256 + threadIdx.x;      // 392 blocks exactly
    int b = m / HWOUT;
    int r = m - b * HWOUT;
    int oy = r / WOUT;
    int ox = r - oy * WOUT;

    const uint32_t* xrow = xp + (((size_t)b * HIN + oy) * WIN2 + ox) * WWORDS;

    uint32_t acc[OGRP];
    #pragma unroll
    for (int i = 0; i < OGRP; ++i) acc[i] = 0u;

    // tap 0 x-words
    uint4 x0 = *(const uint4*)(xrow);
    uint4 x1 = *(const uint4*)(xrow + 4);

    #pragma unroll 1
    for (int tap = 0; tap < TAPS; ++tap) {
        // Prefetch next tap's x-words (last iter re-reads tap 8: harmless).
        int t2 = (tap < TAPS - 1) ? tap + 1 : TAPS - 1;
        int dy2 = t2 / 3;
        int dx2 = t2 - dy2 * 3;
        const uint32_t* nsrc = xrow + (size_t)(dy2 * WIN2 + dx2) * WWORDS;
        uint4 nx0 = *(const uint4*)(nsrc);
        uint4 nx1 = *(const uint4*)(nsrc + 4);

        // Wave-uniform weight base for this (tap, o-group): -> s_load.
        const uint32_t* wt = wq + ((size_t)tap * OCH + obase) * WWORDS;
        #pragma unroll
        for (int oo = 0; oo < OGRP; ++oo) {
            uint4 wa  = *(const uint4*)(wt + oo * 8 + 0);   // words 0-3 (SGPR)
            uint4 wb2 = *(const uint4*)(wt + oo * 8 + 4);   // words 4-7 (SGPR)
            uint32_t t;
            t = wa.x  ^ x0.x; BCNT_ACC(acc[oo], t);
            t = wa.y  ^ x0.y; BCNT_ACC(acc[oo], t);
            t = wa.z  ^ x0.z; BCNT_ACC(acc[oo], t);
            t = wa.w  ^ x0.w; BCNT_ACC(acc[oo], t);
            t = wb2.x ^ x1.x; BCNT_ACC(acc[oo], t);
            t = wb2.y ^ x1.y; BCNT_ACC(acc[oo], t);
            t = wb2.z ^ x1.z; BCNT_ACC(acc[oo], t);
            t = wb2.w ^ x1.w; BCNT_ACC(acc[oo], t);
        }
        x0 = nx0; x1 = nx1;
    }

    size_t ob = ((size_t)b * OCH + obase) * HWOUT + (size_t)oy * WOUT + ox;
    #pragma unroll
    for (int oo = 0; oo < OGRP; ++oo) {
        float P = (float)acc[oo];
        int o0 = obase + oo;
        out[ob + (size_t)oo * HWOUT] = fmaf(sA[o0], P, sB[o0]);
    }
}

// ---------------------------------------------------------------------------
extern "C" void kernel_launch(void* const* d_in, const int* in_sizes, int n_in,
                              void* d_out, int out_size, void* d_ws, size_t ws_size,
                              hipStream_t stream)
{
    const float* x  = (const float*)d_in[0];
    const float* wt = (const float*)d_in[1];
    float* out = (float*)d_out;

    char* ws = (char*)d_ws;
    uint32_t* xp = (uint32_t*)ws;                               // 3,444,736 B
    uint32_t* wq = (uint32_t*)(ws + 3444736);                   //    73,728 B
    float*    sA = (float*)(ws + 3444736 + 73728);              //     1,024 B
    float*    sB = (float*)(ws + 3444736 + 73728 + 1024);       //     1,024 B

    // 1) pack x: 430,592 threads / 256 = 1682 blocks exactly
    pack_x_kernel<<<dim3(1682), dim3(256), 0, stream>>>(x, xp);

    // 2) pack weights (tap-major) + scales
    pack_w_kernel<<<dim3(OCH), dim3(256), 0, stream>>>(wt, wq, sA, sB);

    // 3) main: 392 position-blocks x 8 o-groups of 32
    xnor_main_kernel<<<dim3(392, 8), dim3(256), 0, stream>>>(xp, wq, sA, sB, out);
}